// Round 5
// baseline (684.793 us; speedup 1.0000x reference)
//
#include <hip/hip_runtime.h>
#include <hip/hip_bf16.h>

// B=128, T=512, I=128, H=256, O=1 (fp32 in/out)
// xp = x @ W_ih^T + b_ih + b_hh  (fp32 in ws, 67.1 MB)
// h_t = tanh(xp_t + h @ W_hh^T)  via MFMA: D[n][b] = W_hh · h^T (bf16 in, fp32 acc)
// out = sigmoid(h_T @ W_fc^T + b_fc)

#define B_ 128
#define T_ 512
#define I_ 128
#define H_ 256
#define HP 272   // padded LDS row stride (shorts)

typedef __attribute__((ext_vector_type(8))) short short8;
typedef __attribute__((ext_vector_type(4))) float floatx4;

// fast tanh: 1 - 2*rcp(2^(x*2*log2e) + 1). Raw v_exp/v_rcp (~1ulp), fine for
// bf16-stored h. Saturates correctly: x>+44 -> 1, x<-44 -> -1.
__device__ __forceinline__ float tanh_fast(float x) {
    float e = __builtin_amdgcn_exp2f(x * 2.8853900817779268f);
    float r = __builtin_amdgcn_rcpf(e + 1.0f);
    return __builtin_fmaf(-2.0f, r, 1.0f);
}

// RNE fp32->bf16, finite inputs only (no NaN path)
__device__ __forceinline__ short f2bf(float f) {
    unsigned u = __float_as_uint(f);
    return (short)((u + 0x7FFFu + ((u >> 16) & 1u)) >> 16);
}
// pack two fp32 -> bf16x2 in one dword (RNE, finite)
__device__ __forceinline__ unsigned rne_pack(float a, float b) {
    unsigned ua = __float_as_uint(a), ub = __float_as_uint(b);
    ua = (ua + 0x7FFFu + ((ua >> 16) & 1u)) >> 16;
    ub = (ub + 0x7FFFu + ((ub >> 16) & 1u));
    return (ub & 0xFFFF0000u) | ua;
}

// ---------------- Kernel A: xp[m][n] via 16x16x32 bf16 MFMA, fp32 output.
__global__ __launch_bounds__(256, 1)
void xp_mfma_kernel(const float* __restrict__ x, const float* __restrict__ W_ih,
                    const float* __restrict__ b_ih, const float* __restrict__ b_hh,
                    float* __restrict__ xp) {
    const int tid  = threadIdx.x;
    const int wave = tid >> 6, lane = tid & 63;
    const int l15  = lane & 15, quad = lane >> 4;
    const long m0 = (long)blockIdx.x * 64 + (wave & 1) * 32;
    const int  n0 = (wave >> 1) * 128;

    short8 bfrag[8][4];
#pragma unroll
    for (int nt = 0; nt < 8; ++nt)
#pragma unroll
        for (int kq = 0; kq < 4; ++kq) {
            const float* p = W_ih + (long)(n0 + nt * 16 + l15) * I_ + kq * 32 + quad * 8;
            float4 lo = *(const float4*)(p);
            float4 hi = *(const float4*)(p + 4);
            short8 f;
            f[0] = f2bf(lo.x); f[1] = f2bf(lo.y); f[2] = f2bf(lo.z); f[3] = f2bf(lo.w);
            f[4] = f2bf(hi.x); f[5] = f2bf(hi.y); f[6] = f2bf(hi.z); f[7] = f2bf(hi.w);
            bfrag[nt][kq] = f;
        }

    short8 afrag[2][4];
#pragma unroll
    for (int mt = 0; mt < 2; ++mt)
#pragma unroll
        for (int kq = 0; kq < 4; ++kq) {
            const float* p = x + (m0 + mt * 16 + l15) * I_ + kq * 32 + quad * 8;
            float4 lo = *(const float4*)(p);
            float4 hi = *(const float4*)(p + 4);
            short8 f;
            f[0] = f2bf(lo.x); f[1] = f2bf(lo.y); f[2] = f2bf(lo.z); f[3] = f2bf(lo.w);
            f[4] = f2bf(hi.x); f[5] = f2bf(hi.y); f[6] = f2bf(hi.z); f[7] = f2bf(hi.w);
            afrag[mt][kq] = f;
        }

    floatx4 acc[2][8];
#pragma unroll
    for (int mt = 0; mt < 2; ++mt)
#pragma unroll
        for (int nt = 0; nt < 8; ++nt) acc[mt][nt] = (floatx4){0.f, 0.f, 0.f, 0.f};

#pragma unroll
    for (int kq = 0; kq < 4; ++kq)
#pragma unroll
        for (int mt = 0; mt < 2; ++mt)
#pragma unroll
            for (int nt = 0; nt < 8; ++nt)
                acc[mt][nt] = __builtin_amdgcn_mfma_f32_16x16x32_bf16(
                    afrag[mt][kq], bfrag[nt][kq], acc[mt][nt], 0, 0, 0);

    float biasv[8];
#pragma unroll
    for (int nt = 0; nt < 8; ++nt) {
        int n = n0 + nt * 16 + l15;
        biasv[nt] = b_ih[n] + b_hh[n];
    }
#pragma unroll
    for (int mt = 0; mt < 2; ++mt)
#pragma unroll
        for (int nt = 0; nt < 8; ++nt)
#pragma unroll
            for (int r = 0; r < 4; ++r) {
                long row = m0 + mt * 16 + quad * 4 + r;
                xp[row * H_ + n0 + nt * 16 + l15] = acc[mt][nt][r] + biasv[nt];
            }
}

// ---------------- Kernel B: MFMA recurrence, 4 blocks x 32 batches x 512 thr.
// 8 waves = 2 groups of 16 batches x 4 waves (64 n-cols each) -> 2 waves/SIMD:
// wave A's transcendental epilogue interleaves with wave B's MFMA/FMA issue.
// acc initialized with xp (C-layout == xp-load layout) - no separate add.
__global__ __launch_bounds__(512, 2)
void rnn_kernel(const float* __restrict__ xp, const float* __restrict__ W_hh,
                const float* __restrict__ W_fc, const float* __restrict__ b_fc,
                float* __restrict__ out) {
    __shared__ __align__(16) short hbuf[2][2][16][HP];  // [group][parity][batch][col]
    const int tid  = threadIdx.x;
    const int wave = tid >> 6, lane = tid & 63;
    const int l15  = lane & 15, quad = lane >> 4;
    const int g    = wave >> 2;          // batch-group 0/1
    const int n0   = (wave & 3) * 64;    // output col range
    const int b0   = blockIdx.x * 32;

    // W_hh A-fragments (rows n0..n0+63), resident across all 512 steps
    short8 wfrag[4][8];
#pragma unroll
    for (int mt = 0; mt < 4; ++mt)
#pragma unroll
        for (int kq = 0; kq < 8; ++kq) {
            const float* p = W_hh + (long)(n0 + mt * 16 + l15) * H_ + kq * 32 + quad * 8;
            float4 lo = *(const float4*)(p);
            float4 hi = *(const float4*)(p + 4);
            short8 f;
            f[0] = f2bf(lo.x); f[1] = f2bf(lo.y); f[2] = f2bf(lo.z); f[3] = f2bf(lo.w);
            f[4] = f2bf(hi.x); f[5] = f2bf(hi.y); f[6] = f2bf(hi.z); f[7] = f2bf(hi.w);
            wfrag[mt][kq] = f;
        }

    {   // h_0 = 0 (both groups, both parities)
        int* hz = (int*)hbuf;
#pragma unroll 1
        for (int i = tid; i < (int)(sizeof(hbuf) / 4); i += 512) hz[i] = 0;
    }
    __syncthreads();

    const float* xpl = xp + (long)(b0 + g * 16 + l15) * T_ * H_ + n0 + quad * 4;
    float4 xv[4], xnext[4];
#pragma unroll
    for (int mt = 0; mt < 4; ++mt) xv[mt] = *(const float4*)(xpl + mt * 16);

    const int laneoff = l15 * HP + quad * 8;

#pragma unroll 2
    for (int t = 0; t < T_; ++t) {
        const long tn = (t + 1 < T_) ? (t + 1) : (T_ - 1);
#pragma unroll
        for (int mt = 0; mt < 4; ++mt)
            xnext[mt] = *(const float4*)(xpl + tn * H_ + mt * 16);

        const short* hb = &hbuf[g][t & 1][0][0];
        short8 hfrag[8];
#pragma unroll
        for (int kq = 0; kq < 8; ++kq)
            hfrag[kq] = *(const short8*)(hb + laneoff + kq * 32);

        floatx4 acc[4];
#pragma unroll
        for (int mt = 0; mt < 4; ++mt) {
            acc[mt][0] = xv[mt].x; acc[mt][1] = xv[mt].y;
            acc[mt][2] = xv[mt].z; acc[mt][3] = xv[mt].w;
        }
#pragma unroll
        for (int kq = 0; kq < 8; ++kq)
#pragma unroll
            for (int mt = 0; mt < 4; ++mt)
                acc[mt] = __builtin_amdgcn_mfma_f32_16x16x32_bf16(
                    wfrag[mt][kq], hfrag[kq], acc[mt], 0, 0, 0);

        short* wb = &hbuf[g][(t + 1) & 1][0][0];
#pragma unroll
        for (int mt = 0; mt < 4; ++mt) {
            float y0 = tanh_fast(acc[mt][0]);
            float y1 = tanh_fast(acc[mt][1]);
            float y2 = tanh_fast(acc[mt][2]);
            float y3 = tanh_fast(acc[mt][3]);
            uint2 pk;
            pk.x = rne_pack(y0, y1);
            pk.y = rne_pack(y2, y3);
            *(uint2*)(wb + l15 * HP + n0 + mt * 16 + quad * 4) = pk;
        }
#pragma unroll
        for (int mt = 0; mt < 4; ++mt) xv[mt] = xnext[mt];
        __syncthreads();
    }

    // head: out[b] = sigmoid(b_fc + sum_n h_T[b][n]*W_fc[n]); h_T parity 0 (T even)
    const int bl = tid >> 4, seg = tid & 15;   // bl 0..31, seg 0..15
    const short* hr = &hbuf[bl >> 4][0][bl & 15][seg * 16];
    float p = 0.0f;
#pragma unroll
    for (int i = 0; i < 16; ++i) {
        unsigned u = (unsigned)(unsigned short)hr[i];
        p += __uint_as_float(u << 16) * W_fc[seg * 16 + i];
    }
#pragma unroll
    for (int off = 1; off < 16; off <<= 1) p += __shfl_xor(p, off);
    if (seg == 0) out[b0 + bl] = 1.0f / (1.0f + __expf(-(p + b_fc[0])));
}

extern "C" void kernel_launch(void* const* d_in, const int* in_sizes, int n_in,
                              void* d_out, int out_size, void* d_ws, size_t ws_size,
                              hipStream_t stream) {
    const float* x    = (const float*)d_in[0];
    const float* W_ih = (const float*)d_in[1];
    const float* W_hh = (const float*)d_in[2];
    const float* b_ih = (const float*)d_in[3];
    const float* b_hh = (const float*)d_in[4];
    const float* W_fc = (const float*)d_in[5];
    const float* b_fc = (const float*)d_in[6];
    float* out = (float*)d_out;

    float* xp = (float*)d_ws;   // B*T*H fp32 = 67.1 MB

    xp_mfma_kernel<<<(B_ * T_) / 64, 256, 0, stream>>>(x, W_ih, b_ih, b_hh, xp);
    rnn_kernel<<<B_ / 32, 512, 0, stream>>>(xp, W_hh, W_fc, b_fc, out);
}